// Round 6
// baseline (264.927 us; speedup 1.0000x reference)
//
#include <hip/hip_runtime.h>
#include <math.h>

#ifndef __has_builtin
#define __has_builtin(x) 0
#endif

__device__ __forceinline__ float fsqrt(float x){
#if __has_builtin(__builtin_amdgcn_sqrtf)
    return __builtin_amdgcn_sqrtf(x);
#else
    return sqrtf(x);
#endif
}
__device__ __forceinline__ float frsqrt(float x){
#if __has_builtin(__builtin_amdgcn_rsqf)
    return __builtin_amdgcn_rsqf(x);
#else
    return 1.0f/sqrtf(x);
#endif
}
__device__ __forceinline__ float frcp(float x){
#if __has_builtin(__builtin_amdgcn_rcpf)
    return __builtin_amdgcn_rcpf(x);
#else
    return 1.0f/x;
#endif
}

namespace {
constexpr int TT = 256;
constexpr int BB = 16384;
constexpr float DT  = 0.05f, CD = 0.25f, AP = 0.1f, AV = 0.1f;
constexpr float CJ  = 2.56e-6f;              // CUT*JIT
constexpr float CVV = 1.0f - DT*CD;          // 0.9875
constexpr float WM0 = -0.5625f, WC0 = 1.7975f;
constexpr float W2  = 0.390625f;             // 2*WI ; CUT*W2 == 1.0 exactly
constexpr float WA  = 2.57875f;              // WC0 + 4WI
constexpr float WAC = 6.6016f;               // CUT*WA
constexpr float WCC = 4.6016f;               // CUT*WC0
constexpr float W2E = 0.1171875f;            // W2*0.3
constexpr float RSG = 0.00640512f;           // CUT*(Rd + 2*JIT)
constexpr float CQ2C = 1.53125f;             // CUT*CQ2
constexpr float CB00 = 3.072e-5f;            // CUT*(Q00 + 2JIT)
constexpr float CB11 = 2.6112e-4f;           // CUT*(Q11 + 2JIT)
constexpr float CB22 = 1.024e-5f;            // CUT*(idJIT + Q22 + 2JIT)
constexpr float HCUT = 1.28f;                // 0.5*CUT
constexpr float CUTc = 2.56f;
}

struct UKF {
    float z0v,z1v,z2v,z3v;
    float P00,P01,P02,P03,P11,P12,P13,P22,P23,P33;
    float g00,g10,g20,g30,g11,g21,g31,g22,g32,g33;
    float X00,X01,Xp,Xm,D10,q,D00,D01,D11,D12,D13;
    float B00p,B01p,B02p,B03p,B11p,B12p,B13p,B22p,B23p,B33p;
    const float *yb, *ub; float *ob;
    float2 ynext; float unext;

    __device__ __forceinline__ void load(const float* yg, const float* ug,
                                         const float* z0g, const float* P0g,
                                         float* outg, int b){
        z0v=z0g[b*4+0]; z1v=z0g[b*4+1]; z2v=z0g[b*4+2]; z3v=z0g[b*4+3];
        const float* Pb = P0g + (size_t)b*16;
        P00 = CUTc*Pb[0];
        P01 = HCUT*(Pb[1]+Pb[4]);
        P02 = HCUT*(Pb[2]+Pb[8]);
        P03 = HCUT*(Pb[3]+Pb[12]);
        P11 = CUTc*Pb[5];
        P12 = HCUT*(Pb[6]+Pb[9]);
        P13 = HCUT*(Pb[7]+Pb[13]);
        P22 = CUTc*Pb[10];
        P23 = HCUT*(Pb[11]+Pb[14]);
        P33 = CUTc*Pb[15];
        yb = yg + (size_t)b*TT*2;
        ub = ug + (size_t)b*TT;
        ob = outg + (size_t)b*TT*4;
    }

    // G = chol(Pc + CJ*I)
    __device__ __forceinline__ void chol(){
        float a00 = P00 + CJ;
        float r0  = frsqrt(a00);
        g00 = a00*r0;
        g10 = P01*r0;
        g20 = P02*r0;
        g30 = P03*r0;
        float a11 = fmaf(-g10,g10, P11 + CJ);
        float r1  = frsqrt(a11);
        g11 = a11*r1;
        g21 = fmaf(-g20,g10, P12)*r1;
        g31 = fmaf(-g30,g10, P13)*r1;
        float a22 = fmaf(-g21,g21, fmaf(-g20,g20, P22 + CJ));
        float r2  = frsqrt(a22);
        g22 = a22*r2;
        g32 = fmaf(-g31,g21, fmaf(-g30,g20, P23))*r2;
        float a33 = fmaf(-g32,g32, fmaf(-g31,g31, fmaf(-g30,g30, P33 + CJ)));
        g33 = fsqrt(a33);
    }

    __device__ __forceinline__ void predict0(){
        X00=z0v; X01=z1v; Xp=z1v+g10; Xm=z1v-g10;
        D10=g10; q=0.0f; D00=g00; D01=0.0f; D11=g11; D12=0.0f; D13=0.0f;
        B00p=P00+CJ; B01p=P01; B02p=P02; B03p=P03;
        B11p=P11+CJ; B12p=P12; B13p=P13;
        B22p=P22+CJ; B23p=P23; B33p=P33+CJ;
    }

    __device__ __forceinline__ void predict(float uu){
        // center dynamics
        float w  = z0v*z0v;
        float zc = w*z0v;                        // p^3 at center
        X00 = fmaf(DT, z1v, z0v);
        float ac = fmaf(-CD, z1v, uu);
        ac = fmaf(-z2v, z0v, ac);
        ac = fmaf(-z3v, zc, ac);
        X01 = fmaf(DT, ac, z1v);

        // col0 explicit propagation (comp1 nonlinear)
        float pp = z0v+g00, pm = z0v-g00;
        float vp = z1v+g10, vm = z1v-g10;
        float kp = z2v+g20, km = z2v-g20;
        float aap = z3v+g30, aam = z3v-g30;
        float cp3 = (pp*pp)*pp, cm3 = (pm*pm)*pm;
        float accp = fmaf(-CD, vp, uu); accp = fmaf(-kp,pp,accp); accp = fmaf(-aap,cp3,accp);
        Xp = fmaf(DT, accp, vp);
        float accm = fmaf(-CD, vm, uu); accm = fmaf(-km,pm,accm); accm = fmaf(-aam,cm3,accm);
        Xm = fmaf(DT, accm, vm);
        D10 = 0.5f*(Xp - Xm);
        q   = fmaf(0.5f, Xp + Xm, -X01);

        // odd propagation closed forms
        D00 = fmaf(DT, g10, g00);
        D01 = DT*g11;
        float ha  = fmaf(g31, zc, g21*z0v);
        D11 = fmaf(CVV, g11, -(DT*ha));
        float hb  = fmaf(g32, zc, g22*z0v);
        D12 = -(DT*hb);
        D13 = -(DT*(g33*zc));

        // B' = CUT*P_pred (+ folded consts); CUT*W2 == 1
        B00p = fmaf(D01,D01, fmaf(D00,D00, CB00));
        B01p = fmaf(D01, D11, D00*D10);
        B02p = fmaf(D01, g21, D00*g20);
        B03p = fmaf(D01, g31, D00*g30);
        float TB11 = fmaf(D10,D10, CB11);
        TB11 = fmaf(D11,D11,TB11); TB11 = fmaf(D12,D12,TB11); TB11 = fmaf(D13,D13,TB11);
        B11p = fmaf(CQ2C, q*q, TB11);
        B12p = fmaf(D11,g21, D10*g20); B12p = fmaf(D12,g22,B12p);
        B13p = fmaf(D11,g31, D10*g30); B13p = fmaf(D12,g32,B13p);
        B13p = fmaf(D13,g33,B13p);
        B22p = P22 + CB22;
        B23p = P23;
        B33p = P33 + CB22;
    }

    __device__ __forceinline__ void update(float yv0, float yv1){
        float eps_c = -W2*q;
        float eps_a = q + eps_c;
        float zp1   = fmaf(W2, q, X01);

        float w0 = X00*X00, w1 = X01*X01;
        float apx = AP*X00, avx = AV*X01;
        float Y00 = fmaf(apx, w0, X00);
        float Y01 = fmaf(avx, w1, X01);
        float cp  = fmaf(0.3f, w0, 1.0f);
        float cv  = fmaf(0.3f, w1, 1.0f);
        float e3p = 0.3f*X00, e3v = 0.3f*X01;
        float w2e3p = W2E*X00;

        float D00sq = D00*D00, D01sq = D01*D01;
        float SD0 = D00sq + D01sq;
        float yp0 = fmaf(w2e3p, SD0, Y00);
        float ec0 = Y00 - yp0;
        float xi0 = fmaf(e3p, D00sq, ec0);
        float xi1 = fmaf(e3p, D01sq, ec0);
        float Od00 = D00*fmaf(AP, D00sq, cp);
        float Od01 = D01*fmaf(AP, D01sq, cp);

        float sp = Xp*Xp, sm = Xm*Xm;
        float Yp = fmaf(AV*Xp, sp, Xp);
        float Ym = fmaf(AV*Xm, sm, Xm);
        float qy = fmaf(0.5f, Yp + Ym, -Y01);
        float Q0 = 0.5f*(Yp - Ym);

        float D11sq = D11*D11, D12sq = D12*D12, D13sq = D13*D13;
        float SD1 = (D11sq + D12sq) + D13sq;
        float inner = fmaf(e3v, SD1, qy);
        float yp1 = fmaf(W2, inner, Y01);
        float ec1 = Y01 - yp1;
        float et0 = qy + ec1;
        float et1 = fmaf(e3v, D11sq, ec1);
        float et2 = fmaf(e3v, D12sq, ec1);
        float et3 = fmaf(e3v, D13sq, ec1);
        float Q1 = D11*fmaf(AV, D11sq, cv);
        float Q2 = D12*fmaf(AV, D12sq, cv);
        float Q3 = D13*fmaf(AV, D13sq, cv);
        float et23 = et2 + et3;

        // S' = CUT*S
        float Ts00 = fmaf(Od00,Od00, xi0*xi0);
        Ts00 = fmaf(xi1,xi1,Ts00); Ts00 = fmaf(Od01,Od01,Ts00);
        float s00 = fmaf(WAC, ec0*ec0, Ts00);
        float Ts01 = fmaf(Od00, Q0, xi0*et0);
        Ts01 = fmaf(xi1, et1, Ts01); Ts01 = fmaf(Od01, Q1, Ts01);
        Ts01 = fmaf(ec0, et23, Ts01);
        float s01 = fmaf(WCC, ec0*ec1, Ts01);
        float Ts11 = fmaf(Q0,Q0, et0*et0);
        Ts11 = fmaf(et1,et1,Ts11); Ts11 = fmaf(Q1,Q1,Ts11);
        Ts11 = fmaf(et2,et2,Ts11); Ts11 = fmaf(Q2,Q2,Ts11);
        Ts11 = fmaf(et3,et3,Ts11); Ts11 = fmaf(Q3,Q3,Ts11);
        float s11 = fmaf(WCC, ec1*ec1, Ts11);

        // pz' = CUT*P_zy
        float pz00 = fmaf(D01, Od01, D00*Od00);
        float pz01 = fmaf(D01, Q1, D00*Q0);
        float Tp10 = fmaf(D10, Od00, eps_a*xi0);
        Tp10 = fmaf(eps_c, xi1, Tp10); Tp10 = fmaf(D11, Od01, Tp10);
        float pz10 = fmaf(-WA, q*ec0, Tp10);
        float et123 = et1 + et23;
        float Tp11 = fmaf(D10, Q0, eps_a*et0);
        Tp11 = fmaf(eps_c, et123, Tp11);
        Tp11 = fmaf(D11, Q1, Tp11);
        Tp11 = fmaf(D12, Q2, Tp11);
        Tp11 = fmaf(D13, Q3, Tp11);
        float pz11 = fmaf(-WC0, q*ec1, Tp11);
        float pz20 = fmaf(g21, Od01, g20*Od00);
        float pz30 = fmaf(g31, Od01, g30*Od00);
        float pz21 = fmaf(g21, Q1, g20*Q0); pz21 = fmaf(g22, Q2, pz21);
        float pz31 = fmaf(g31, Q1, g30*Q0); pz31 = fmaf(g32, Q2, pz31);
        pz31 = fmaf(g33, Q3, pz31);

        // K = pz' * (S')^-1 (true gain; CUT cancels)
        float sg00 = s00 + RSG, sg11 = s11 + RSG;
        float det  = fmaf(sg00, sg11, -(s01*s01));
        float idet = frcp(det);
        float i00 = sg11*idet, i01 = -(s01*idet), i11 = sg00*idet;
        float K00 = fmaf(pz01,i01, pz00*i00), K01 = fmaf(pz01,i11, pz00*i01);
        float K10 = fmaf(pz11,i01, pz10*i00), K11 = fmaf(pz11,i11, pz10*i01);
        float K20 = fmaf(pz21,i01, pz20*i00), K21 = fmaf(pz21,i11, pz20*i01);
        float K30 = fmaf(pz31,i01, pz30*i00), K31 = fmaf(pz31,i11, pz30*i01);

        float nu0 = yv0 - yp0, nu1 = yv1 - yp1;
        z0v = fmaf(K00,nu0, fmaf(K01,nu1, X00));
        z1v = fmaf(K10,nu0, fmaf(K11,nu1, zp1));
        z2v = fmaf(K20,nu0, fmaf(K21,nu1, z2v));
        z3v = fmaf(K30,nu0, fmaf(K31,nu1, z3v));

        // Pc_post = B' - K*pz'^T
        P00 = fmaf(-K00,pz00, fmaf(-K01,pz01, B00p));
        P01 = fmaf(-K00,pz10, fmaf(-K01,pz11, B01p));
        P02 = fmaf(-K00,pz20, fmaf(-K01,pz21, B02p));
        P03 = fmaf(-K00,pz30, fmaf(-K01,pz31, B03p));
        P11 = fmaf(-K10,pz10, fmaf(-K11,pz11, B11p));
        P12 = fmaf(-K10,pz20, fmaf(-K11,pz21, B12p));
        P13 = fmaf(-K10,pz30, fmaf(-K11,pz31, B13p));
        P22 = fmaf(-K20,pz20, fmaf(-K21,pz21, B22p));
        P23 = fmaf(-K20,pz30, fmaf(-K21,pz31, B23p));
        P33 = fmaf(-K30,pz30, fmaf(-K31,pz31, B33p));
    }

    __device__ __forceinline__ void store(int t){
        *reinterpret_cast<float4*>(ob + 4*t) = make_float4(z0v,z1v,z2v,z3v);
    }
};

__global__ __launch_bounds__(64)
void ukf_kernel(const float* __restrict__ yg, const float* __restrict__ ug,
                const float* __restrict__ z0g, const float* __restrict__ P0g,
                float* __restrict__ outg)
{
    const int tid = blockIdx.x*64 + threadIdx.x;

    UKF A, B;
    A.load(yg,ug,z0g,P0g,outg, tid);
    B.load(yg,ug,z0g,P0g,outg, tid + BB/2);

    float2 ayc = *reinterpret_cast<const float2*>(A.yb);
    float2 byc = *reinterpret_cast<const float2*>(B.yb);
    A.ynext = *reinterpret_cast<const float2*>(A.yb + 2);
    B.ynext = *reinterpret_cast<const float2*>(B.yb + 2);
    A.unext = A.ub[0];
    B.unext = B.ub[0];

    // ---- t = 0 (no dynamics) ----
    A.chol();               B.chol();
    A.predict0();           B.predict0();
    A.update(ayc.x, ayc.y); B.update(byc.x, byc.y);
    A.store(0);             B.store(0);

    // ---- main loop t = 1..255, two independent filters interleaved ----
    #pragma unroll 1
    for (int t = 1; t < TT; ++t) {
        float ay0=A.ynext.x, ay1=A.ynext.y, au=A.unext;
        float by0=B.ynext.x, by1=B.ynext.y, bu=B.unext;
        int tn = (t+1 < TT) ? (t+1) : (TT-1);
        A.ynext = *reinterpret_cast<const float2*>(A.yb + 2*tn);
        B.ynext = *reinterpret_cast<const float2*>(B.yb + 2*tn);
        A.unext = A.ub[t];
        B.unext = B.ub[t];

        A.chol();            B.chol();
        A.predict(au);       B.predict(bu);
        A.update(ay0, ay1);  B.update(by0, by1);
        A.store(t);          B.store(t);
    }
}

extern "C" void kernel_launch(void* const* d_in, const int* in_sizes, int n_in,
                              void* d_out, int out_size, void* d_ws, size_t ws_size,
                              hipStream_t stream) {
    const float* y  = (const float*)d_in[0];   // (B,T,NY)
    const float* u  = (const float*)d_in[1];   // (B,T)
    const float* z0 = (const float*)d_in[2];   // (B,N)
    const float* P0 = (const float*)d_in[3];   // (B,N,N)
    float* out = (float*)d_out;                // (B,T,N)

    ukf_kernel<<<dim3((BB/2)/64), dim3(64), 0, stream>>>(y, u, z0, P0, out);
}

// Round 7
// 264.485 us; speedup vs baseline: 1.0017x; 1.0017x over previous
//
#include <hip/hip_runtime.h>
#include <math.h>

#ifndef __has_builtin
#define __has_builtin(x) 0
#endif

__device__ __forceinline__ float fsqrt(float x){
#if __has_builtin(__builtin_amdgcn_sqrtf)
    return __builtin_amdgcn_sqrtf(x);
#else
    return sqrtf(x);
#endif
}
__device__ __forceinline__ float frsqrt(float x){
#if __has_builtin(__builtin_amdgcn_rsqf)
    return __builtin_amdgcn_rsqf(x);
#else
    return 1.0f/sqrtf(x);
#endif
}
__device__ __forceinline__ float frcp(float x){
#if __has_builtin(__builtin_amdgcn_rcpf)
    return __builtin_amdgcn_rcpf(x);
#else
    return 1.0f/x;
#endif
}

namespace {
constexpr int TT = 256;
constexpr int BB = 16384;
constexpr float DT  = 0.05f, CD = 0.25f, AP = 0.1f, AV = 0.1f;
constexpr float CJ  = 2.56e-6f;              // CUT*JIT
constexpr float CVV = 1.0f - DT*CD;          // 0.9875
constexpr float WM0 = -0.5625f, WC0 = 1.7975f;
constexpr float W2  = 0.390625f;             // 2*WI ; CUT*W2 == 1.0 exactly
constexpr float WA  = 2.57875f;              // WC0 + 4WI
constexpr float WAC = 6.6016f;               // CUT*WA
constexpr float WCC = 4.6016f;               // CUT*WC0
constexpr float W2E = 0.1171875f;            // W2*0.3
constexpr float RSG = 0.00640512f;           // CUT*(Rd + 2*JIT)
constexpr float CQ2C = 1.53125f;             // CUT*CQ2
constexpr float CB00 = 3.072e-5f;            // CUT*(Q00 + 2JIT)
constexpr float CB11 = 2.6112e-4f;           // CUT*(Q11 + 2JIT)
constexpr float CB22 = 1.024e-5f;            // CUT*(idJIT + Q22 + 2JIT)
constexpr float HCUT = 1.28f;                // 0.5*CUT
constexpr float CUTc = 2.56f;
}

struct UKF {
    float z0v,z1v,z2v,z3v;
    float P00,P01,P02,P03,P11,P12,P13,P22,P23,P33;
    float g00,g10,g20,g30,g11,g21,g31,g22,g32,g33;
    float X00,X01,Xp,Xm,D10,q,D00,D01,D11,D12,D13;
    float B00p,B01p,B02p,B03p,B11p,B12p,B13p,B22p,B23p,B33p;
    const float *yb, *ub; float *ob;
    float2 ynext; float unext;

    __device__ __forceinline__ void load(const float* yg, const float* ug,
                                         const float* z0g, const float* P0g,
                                         float* outg, int b){
        z0v=z0g[b*4+0]; z1v=z0g[b*4+1]; z2v=z0g[b*4+2]; z3v=z0g[b*4+3];
        const float* Pb = P0g + (size_t)b*16;
        P00 = CUTc*Pb[0];
        P01 = HCUT*(Pb[1]+Pb[4]);
        P02 = HCUT*(Pb[2]+Pb[8]);
        P03 = HCUT*(Pb[3]+Pb[12]);
        P11 = CUTc*Pb[5];
        P12 = HCUT*(Pb[6]+Pb[9]);
        P13 = HCUT*(Pb[7]+Pb[13]);
        P22 = CUTc*Pb[10];
        P23 = HCUT*(Pb[11]+Pb[14]);
        P33 = CUTc*Pb[15];
        yb = yg + (size_t)b*TT*2;
        ub = ug + (size_t)b*TT;
        ob = outg + (size_t)b*TT*4;
    }

    // G = chol(Pc + CJ*I)
    __device__ __forceinline__ void chol(){
        float a00 = P00 + CJ;
        float r0  = frsqrt(a00);
        g00 = a00*r0;
        g10 = P01*r0;
        g20 = P02*r0;
        g30 = P03*r0;
        float a11 = fmaf(-g10,g10, P11 + CJ);
        float r1  = frsqrt(a11);
        g11 = a11*r1;
        g21 = fmaf(-g20,g10, P12)*r1;
        g31 = fmaf(-g30,g10, P13)*r1;
        float a22 = fmaf(-g21,g21, fmaf(-g20,g20, P22 + CJ));
        float r2  = frsqrt(a22);
        g22 = a22*r2;
        g32 = fmaf(-g31,g21, fmaf(-g30,g20, P23))*r2;
        float a33 = fmaf(-g32,g32, fmaf(-g31,g31, fmaf(-g30,g30, P33 + CJ)));
        g33 = fsqrt(a33);
    }

    __device__ __forceinline__ void predict0(){
        X00=z0v; X01=z1v; Xp=z1v+g10; Xm=z1v-g10;
        D10=g10; q=0.0f; D00=g00; D01=0.0f; D11=g11; D12=0.0f; D13=0.0f;
        B00p=P00+CJ; B01p=P01; B02p=P02; B03p=P03;
        B11p=P11+CJ; B12p=P12; B13p=P13;
        B22p=P22+CJ; B23p=P23; B33p=P33+CJ;
    }

    __device__ __forceinline__ void predict(float uu){
        // center dynamics
        float w  = z0v*z0v;
        float zc = w*z0v;                        // p^3 at center
        X00 = fmaf(DT, z1v, z0v);
        float ac = fmaf(-CD, z1v, uu);
        ac = fmaf(-z2v, z0v, ac);
        ac = fmaf(-z3v, zc, ac);
        X01 = fmaf(DT, ac, z1v);

        // col0 explicit propagation (comp1 nonlinear)
        float pp = z0v+g00, pm = z0v-g00;
        float vp = z1v+g10, vm = z1v-g10;
        float kp = z2v+g20, km = z2v-g20;
        float aap = z3v+g30, aam = z3v-g30;
        float cp3 = (pp*pp)*pp, cm3 = (pm*pm)*pm;
        float accp = fmaf(-CD, vp, uu); accp = fmaf(-kp,pp,accp); accp = fmaf(-aap,cp3,accp);
        Xp = fmaf(DT, accp, vp);
        float accm = fmaf(-CD, vm, uu); accm = fmaf(-km,pm,accm); accm = fmaf(-aam,cm3,accm);
        Xm = fmaf(DT, accm, vm);
        D10 = 0.5f*(Xp - Xm);
        q   = fmaf(0.5f, Xp + Xm, -X01);

        // odd propagation closed forms
        D00 = fmaf(DT, g10, g00);
        D01 = DT*g11;
        float ha  = fmaf(g31, zc, g21*z0v);
        D11 = fmaf(CVV, g11, -(DT*ha));
        float hb  = fmaf(g32, zc, g22*z0v);
        D12 = -(DT*hb);
        D13 = -(DT*(g33*zc));

        // B' = CUT*P_pred (+ folded consts); CUT*W2 == 1
        B00p = fmaf(D01,D01, fmaf(D00,D00, CB00));
        B01p = fmaf(D01, D11, D00*D10);
        B02p = fmaf(D01, g21, D00*g20);
        B03p = fmaf(D01, g31, D00*g30);
        float TB11 = fmaf(D10,D10, CB11);
        TB11 = fmaf(D11,D11,TB11); TB11 = fmaf(D12,D12,TB11); TB11 = fmaf(D13,D13,TB11);
        B11p = fmaf(CQ2C, q*q, TB11);
        B12p = fmaf(D11,g21, D10*g20); B12p = fmaf(D12,g22,B12p);
        B13p = fmaf(D11,g31, D10*g30); B13p = fmaf(D12,g32,B13p);
        B13p = fmaf(D13,g33,B13p);
        B22p = P22 + CB22;
        B23p = P23;
        B33p = P33 + CB22;
    }

    __device__ __forceinline__ void update(float yv0, float yv1){
        float eps_c = -W2*q;
        float eps_a = q + eps_c;
        float zp1   = fmaf(W2, q, X01);

        float w0 = X00*X00, w1 = X01*X01;
        float apx = AP*X00, avx = AV*X01;
        float Y00 = fmaf(apx, w0, X00);
        float Y01 = fmaf(avx, w1, X01);
        float cp  = fmaf(0.3f, w0, 1.0f);
        float cv  = fmaf(0.3f, w1, 1.0f);
        float e3p = 0.3f*X00, e3v = 0.3f*X01;
        float w2e3p = W2E*X00;

        float D00sq = D00*D00, D01sq = D01*D01;
        float SD0 = D00sq + D01sq;
        float yp0 = fmaf(w2e3p, SD0, Y00);
        float ec0 = Y00 - yp0;
        float xi0 = fmaf(e3p, D00sq, ec0);
        float xi1 = fmaf(e3p, D01sq, ec0);
        float Od00 = D00*fmaf(AP, D00sq, cp);
        float Od01 = D01*fmaf(AP, D01sq, cp);

        float sp = Xp*Xp, sm = Xm*Xm;
        float Yp = fmaf(AV*Xp, sp, Xp);
        float Ym = fmaf(AV*Xm, sm, Xm);
        float qy = fmaf(0.5f, Yp + Ym, -Y01);
        float Q0 = 0.5f*(Yp - Ym);

        float D11sq = D11*D11, D12sq = D12*D12, D13sq = D13*D13;
        float SD1 = (D11sq + D12sq) + D13sq;
        float inner = fmaf(e3v, SD1, qy);
        float yp1 = fmaf(W2, inner, Y01);
        float ec1 = Y01 - yp1;
        float et0 = qy + ec1;
        float et1 = fmaf(e3v, D11sq, ec1);
        float et2 = fmaf(e3v, D12sq, ec1);
        float et3 = fmaf(e3v, D13sq, ec1);
        float Q1 = D11*fmaf(AV, D11sq, cv);
        float Q2 = D12*fmaf(AV, D12sq, cv);
        float Q3 = D13*fmaf(AV, D13sq, cv);
        float et23 = et2 + et3;

        // S' = CUT*S
        float Ts00 = fmaf(Od00,Od00, xi0*xi0);
        Ts00 = fmaf(xi1,xi1,Ts00); Ts00 = fmaf(Od01,Od01,Ts00);
        float s00 = fmaf(WAC, ec0*ec0, Ts00);
        float Ts01 = fmaf(Od00, Q0, xi0*et0);
        Ts01 = fmaf(xi1, et1, Ts01); Ts01 = fmaf(Od01, Q1, Ts01);
        Ts01 = fmaf(ec0, et23, Ts01);
        float s01 = fmaf(WCC, ec0*ec1, Ts01);
        float Ts11 = fmaf(Q0,Q0, et0*et0);
        Ts11 = fmaf(et1,et1,Ts11); Ts11 = fmaf(Q1,Q1,Ts11);
        Ts11 = fmaf(et2,et2,Ts11); Ts11 = fmaf(Q2,Q2,Ts11);
        Ts11 = fmaf(et3,et3,Ts11); Ts11 = fmaf(Q3,Q3,Ts11);
        float s11 = fmaf(WCC, ec1*ec1, Ts11);

        // pz' = CUT*P_zy
        float pz00 = fmaf(D01, Od01, D00*Od00);
        float pz01 = fmaf(D01, Q1, D00*Q0);
        float Tp10 = fmaf(D10, Od00, eps_a*xi0);
        Tp10 = fmaf(eps_c, xi1, Tp10); Tp10 = fmaf(D11, Od01, Tp10);
        float pz10 = fmaf(-WA, q*ec0, Tp10);
        float et123 = et1 + et23;
        float Tp11 = fmaf(D10, Q0, eps_a*et0);
        Tp11 = fmaf(eps_c, et123, Tp11);
        Tp11 = fmaf(D11, Q1, Tp11);
        Tp11 = fmaf(D12, Q2, Tp11);
        Tp11 = fmaf(D13, Q3, Tp11);
        float pz11 = fmaf(-WC0, q*ec1, Tp11);
        float pz20 = fmaf(g21, Od01, g20*Od00);
        float pz30 = fmaf(g31, Od01, g30*Od00);
        float pz21 = fmaf(g21, Q1, g20*Q0); pz21 = fmaf(g22, Q2, pz21);
        float pz31 = fmaf(g31, Q1, g30*Q0); pz31 = fmaf(g32, Q2, pz31);
        pz31 = fmaf(g33, Q3, pz31);

        // K = pz' * (S')^-1 (true gain; CUT cancels)
        float sg00 = s00 + RSG, sg11 = s11 + RSG;
        float det  = fmaf(sg00, sg11, -(s01*s01));
        float idet = frcp(det);
        float i00 = sg11*idet, i01 = -(s01*idet), i11 = sg00*idet;
        float K00 = fmaf(pz01,i01, pz00*i00), K01 = fmaf(pz01,i11, pz00*i01);
        float K10 = fmaf(pz11,i01, pz10*i00), K11 = fmaf(pz11,i11, pz10*i01);
        float K20 = fmaf(pz21,i01, pz20*i00), K21 = fmaf(pz21,i11, pz20*i01);
        float K30 = fmaf(pz31,i01, pz30*i00), K31 = fmaf(pz31,i11, pz30*i01);

        float nu0 = yv0 - yp0, nu1 = yv1 - yp1;
        z0v = fmaf(K00,nu0, fmaf(K01,nu1, X00));
        z1v = fmaf(K10,nu0, fmaf(K11,nu1, zp1));
        z2v = fmaf(K20,nu0, fmaf(K21,nu1, z2v));
        z3v = fmaf(K30,nu0, fmaf(K31,nu1, z3v));

        // Pc_post = B' - K*pz'^T
        P00 = fmaf(-K00,pz00, fmaf(-K01,pz01, B00p));
        P01 = fmaf(-K00,pz10, fmaf(-K01,pz11, B01p));
        P02 = fmaf(-K00,pz20, fmaf(-K01,pz21, B02p));
        P03 = fmaf(-K00,pz30, fmaf(-K01,pz31, B03p));
        P11 = fmaf(-K10,pz10, fmaf(-K11,pz11, B11p));
        P12 = fmaf(-K10,pz20, fmaf(-K11,pz21, B12p));
        P13 = fmaf(-K10,pz30, fmaf(-K11,pz31, B13p));
        P22 = fmaf(-K20,pz20, fmaf(-K21,pz21, B22p));
        P23 = fmaf(-K20,pz30, fmaf(-K21,pz31, B23p));
        P33 = fmaf(-K30,pz30, fmaf(-K31,pz31, B33p));
    }

    __device__ __forceinline__ void store(int t){
        *reinterpret_cast<float4*>(ob + 4*t) = make_float4(z0v,z1v,z2v,z3v);
    }
};

// (64, 1): 1 wave min per SIMD -> full VGPR file available to this wave.
// R6 regression root-cause: default occupancy target capped VGPRs at 48 and
// spilled the second filter's state to scratch (WRITE_SIZE 70->174 MB).
__global__ __launch_bounds__(64, 1)
void ukf_kernel(const float* __restrict__ yg, const float* __restrict__ ug,
                const float* __restrict__ z0g, const float* __restrict__ P0g,
                float* __restrict__ outg)
{
    const int tid = blockIdx.x*64 + threadIdx.x;

    UKF A, B;
    A.load(yg,ug,z0g,P0g,outg, tid);
    B.load(yg,ug,z0g,P0g,outg, tid + BB/2);

    float2 ayc = *reinterpret_cast<const float2*>(A.yb);
    float2 byc = *reinterpret_cast<const float2*>(B.yb);
    A.ynext = *reinterpret_cast<const float2*>(A.yb + 2);
    B.ynext = *reinterpret_cast<const float2*>(B.yb + 2);
    A.unext = A.ub[0];
    B.unext = B.ub[0];

    // ---- t = 0 (no dynamics) ----
    A.chol();               B.chol();
    A.predict0();           B.predict0();
    A.update(ayc.x, ayc.y); B.update(byc.x, byc.y);
    A.store(0);             B.store(0);

    // ---- main loop t = 1..255, two independent filters interleaved ----
    #pragma unroll 1
    for (int t = 1; t < TT; ++t) {
        float ay0=A.ynext.x, ay1=A.ynext.y, au=A.unext;
        float by0=B.ynext.x, by1=B.ynext.y, bu=B.unext;
        int tn = (t+1 < TT) ? (t+1) : (TT-1);
        A.ynext = *reinterpret_cast<const float2*>(A.yb + 2*tn);
        B.ynext = *reinterpret_cast<const float2*>(B.yb + 2*tn);
        A.unext = A.ub[t];
        B.unext = B.ub[t];

        A.chol();            B.chol();
        A.predict(au);       B.predict(bu);
        A.update(ay0, ay1);  B.update(by0, by1);
        A.store(t);          B.store(t);
    }
}

extern "C" void kernel_launch(void* const* d_in, const int* in_sizes, int n_in,
                              void* d_out, int out_size, void* d_ws, size_t ws_size,
                              hipStream_t stream) {
    const float* y  = (const float*)d_in[0];   // (B,T,NY)
    const float* u  = (const float*)d_in[1];   // (B,T)
    const float* z0 = (const float*)d_in[2];   // (B,N)
    const float* P0 = (const float*)d_in[3];   // (B,N,N)
    float* out = (float*)d_out;                // (B,T,N)

    ukf_kernel<<<dim3((BB/2)/64), dim3(64), 0, stream>>>(y, u, z0, P0, out);
}

// Round 8
// 226.515 us; speedup vs baseline: 1.1696x; 1.1676x over previous
//
#include <hip/hip_runtime.h>
#include <math.h>

#ifndef __has_builtin
#define __has_builtin(x) 0
#endif

__device__ __forceinline__ float fsqrt(float x){
#if __has_builtin(__builtin_amdgcn_sqrtf)
    return __builtin_amdgcn_sqrtf(x);
#else
    return sqrtf(x);
#endif
}
__device__ __forceinline__ float frsqrt(float x){
#if __has_builtin(__builtin_amdgcn_rsqf)
    return __builtin_amdgcn_rsqf(x);
#else
    return 1.0f/sqrtf(x);
#endif
}
__device__ __forceinline__ float frcp(float x){
#if __has_builtin(__builtin_amdgcn_rcpf)
    return __builtin_amdgcn_rcpf(x);
#else
    return 1.0f/x;
#endif
}

namespace {
constexpr int TT = 256;
constexpr int BB = 16384;
constexpr float DT  = 0.05f, CD = 0.25f, AP = 0.1f, AV = 0.1f;
constexpr float CJ  = 2.56e-6f;              // CUT*JIT
constexpr float CVV = 1.0f - DT*CD;          // 0.9875
constexpr float WM0 = -0.5625f, WC0 = 1.7975f;
constexpr float W2  = 0.390625f;             // 2*WI ; CUT*W2 == 1.0 exactly
constexpr float WA  = 2.57875f;              // WC0 + 4WI
constexpr float WAC = 6.6016f;               // CUT*WA
constexpr float WCC = 4.6016f;               // CUT*WC0
constexpr float W2E = 0.1171875f;            // W2*0.3
constexpr float RSG = 0.00640512f;           // CUT*(Rd + 2*JIT)
constexpr float CQ2C = 1.53125f;             // CUT*CQ2
constexpr float CB00 = 3.072e-5f;            // CUT*(Q00 + 2JIT)
constexpr float CB11 = 2.6112e-4f;           // CUT*(Q11 + 2JIT)
constexpr float CB22 = 1.024e-5f;            // CUT*(idJIT + Q22 + 2JIT)
constexpr float HCUT = 1.28f;                // 0.5*CUT
constexpr float CUTc = 2.56f;
}

struct UKF {
    float z0v,z1v,z2v,z3v;
    float P00,P01,P02,P03,P11,P12,P13,P22,P23,P33;
    float g00,g10,g20,g30,g11,g21,g31,g22,g32,g33;
    float X00,X01,Xp,Xm,D10,q,D00,D01,D11,D12,D13;
    float B00p,B01p,B02p,B03p,B11p,B12p,B13p,B22p,B23p,B33p;
    const float *yb, *ub; float *ob;
    float2 ynext; float unext;

    __device__ __forceinline__ void load(const float* yg, const float* ug,
                                         const float* z0g, const float* P0g,
                                         float* outg, int b){
        z0v=z0g[b*4+0]; z1v=z0g[b*4+1]; z2v=z0g[b*4+2]; z3v=z0g[b*4+3];
        const float* Pb = P0g + (size_t)b*16;
        P00 = CUTc*Pb[0];
        P01 = HCUT*(Pb[1]+Pb[4]);
        P02 = HCUT*(Pb[2]+Pb[8]);
        P03 = HCUT*(Pb[3]+Pb[12]);
        P11 = CUTc*Pb[5];
        P12 = HCUT*(Pb[6]+Pb[9]);
        P13 = HCUT*(Pb[7]+Pb[13]);
        P22 = CUTc*Pb[10];
        P23 = HCUT*(Pb[11]+Pb[14]);
        P33 = CUTc*Pb[15];
        yb = yg + (size_t)b*TT*2;
        ub = ug + (size_t)b*TT;
        ob = outg + (size_t)b*TT*4;
    }

    // G = chol(Pc + CJ*I)
    __device__ __forceinline__ void chol(){
        float a00 = P00 + CJ;
        float r0  = frsqrt(a00);
        g00 = a00*r0;
        g10 = P01*r0;
        g20 = P02*r0;
        g30 = P03*r0;
        float a11 = fmaf(-g10,g10, P11 + CJ);
        float r1  = frsqrt(a11);
        g11 = a11*r1;
        g21 = fmaf(-g20,g10, P12)*r1;
        g31 = fmaf(-g30,g10, P13)*r1;
        float a22 = fmaf(-g21,g21, fmaf(-g20,g20, P22 + CJ));
        float r2  = frsqrt(a22);
        g22 = a22*r2;
        g32 = fmaf(-g31,g21, fmaf(-g30,g20, P23))*r2;
        float a33 = fmaf(-g32,g32, fmaf(-g31,g31, fmaf(-g30,g30, P33 + CJ)));
        g33 = fsqrt(a33);
    }

    __device__ __forceinline__ void predict0(){
        X00=z0v; X01=z1v; Xp=z1v+g10; Xm=z1v-g10;
        D10=g10; q=0.0f; D00=g00; D01=0.0f; D11=g11; D12=0.0f; D13=0.0f;
        B00p=P00+CJ; B01p=P01; B02p=P02; B03p=P03;
        B11p=P11+CJ; B12p=P12; B13p=P13;
        B22p=P22+CJ; B23p=P23; B33p=P33+CJ;
    }

    __device__ __forceinline__ void predict(float uu){
        // center dynamics
        float w  = z0v*z0v;
        float zc = w*z0v;                        // p^3 at center
        X00 = fmaf(DT, z1v, z0v);
        float ac = fmaf(-CD, z1v, uu);
        ac = fmaf(-z2v, z0v, ac);
        ac = fmaf(-z3v, zc, ac);
        X01 = fmaf(DT, ac, z1v);

        // col0 explicit propagation (comp1 nonlinear)
        float pp = z0v+g00, pm = z0v-g00;
        float vp = z1v+g10, vm = z1v-g10;
        float kp = z2v+g20, km = z2v-g20;
        float aap = z3v+g30, aam = z3v-g30;
        float cp3 = (pp*pp)*pp, cm3 = (pm*pm)*pm;
        float accp = fmaf(-CD, vp, uu); accp = fmaf(-kp,pp,accp); accp = fmaf(-aap,cp3,accp);
        Xp = fmaf(DT, accp, vp);
        float accm = fmaf(-CD, vm, uu); accm = fmaf(-km,pm,accm); accm = fmaf(-aam,cm3,accm);
        Xm = fmaf(DT, accm, vm);
        D10 = 0.5f*(Xp - Xm);
        q   = fmaf(0.5f, Xp + Xm, -X01);

        // odd propagation closed forms
        D00 = fmaf(DT, g10, g00);
        D01 = DT*g11;
        float ha  = fmaf(g31, zc, g21*z0v);
        D11 = fmaf(CVV, g11, -(DT*ha));
        float hb  = fmaf(g32, zc, g22*z0v);
        D12 = -(DT*hb);
        D13 = -(DT*(g33*zc));

        // B' = CUT*P_pred (+ folded consts); CUT*W2 == 1
        B00p = fmaf(D01,D01, fmaf(D00,D00, CB00));
        B01p = fmaf(D01, D11, D00*D10);
        B02p = fmaf(D01, g21, D00*g20);
        B03p = fmaf(D01, g31, D00*g30);
        float TB11 = fmaf(D10,D10, CB11);
        TB11 = fmaf(D11,D11,TB11); TB11 = fmaf(D12,D12,TB11); TB11 = fmaf(D13,D13,TB11);
        B11p = fmaf(CQ2C, q*q, TB11);
        B12p = fmaf(D11,g21, D10*g20); B12p = fmaf(D12,g22,B12p);
        B13p = fmaf(D11,g31, D10*g30); B13p = fmaf(D12,g32,B13p);
        B13p = fmaf(D13,g33,B13p);
        B22p = P22 + CB22;
        B23p = P23;
        B33p = P33 + CB22;
    }

    __device__ __forceinline__ void update(float yv0, float yv1){
        float eps_c = -W2*q;
        float eps_a = q + eps_c;
        float zp1   = fmaf(W2, q, X01);

        float w0 = X00*X00, w1 = X01*X01;
        float apx = AP*X00, avx = AV*X01;
        float Y00 = fmaf(apx, w0, X00);
        float Y01 = fmaf(avx, w1, X01);
        float cp  = fmaf(0.3f, w0, 1.0f);
        float cv  = fmaf(0.3f, w1, 1.0f);
        float e3p = 0.3f*X00, e3v = 0.3f*X01;
        float w2e3p = W2E*X00;

        float D00sq = D00*D00, D01sq = D01*D01;
        float SD0 = D00sq + D01sq;
        float yp0 = fmaf(w2e3p, SD0, Y00);
        float ec0 = Y00 - yp0;
        float xi0 = fmaf(e3p, D00sq, ec0);
        float xi1 = fmaf(e3p, D01sq, ec0);
        float Od00 = D00*fmaf(AP, D00sq, cp);
        float Od01 = D01*fmaf(AP, D01sq, cp);

        float sp = Xp*Xp, sm = Xm*Xm;
        float Yp = fmaf(AV*Xp, sp, Xp);
        float Ym = fmaf(AV*Xm, sm, Xm);
        float qy = fmaf(0.5f, Yp + Ym, -Y01);
        float Q0 = 0.5f*(Yp - Ym);

        float D11sq = D11*D11, D12sq = D12*D12, D13sq = D13*D13;
        float SD1 = (D11sq + D12sq) + D13sq;
        float inner = fmaf(e3v, SD1, qy);
        float yp1 = fmaf(W2, inner, Y01);
        float ec1 = Y01 - yp1;
        float et0 = qy + ec1;
        float et1 = fmaf(e3v, D11sq, ec1);
        float et2 = fmaf(e3v, D12sq, ec1);
        float et3 = fmaf(e3v, D13sq, ec1);
        float Q1 = D11*fmaf(AV, D11sq, cv);
        float Q2 = D12*fmaf(AV, D12sq, cv);
        float Q3 = D13*fmaf(AV, D13sq, cv);
        float et23 = et2 + et3;

        // S' = CUT*S
        float Ts00 = fmaf(Od00,Od00, xi0*xi0);
        Ts00 = fmaf(xi1,xi1,Ts00); Ts00 = fmaf(Od01,Od01,Ts00);
        float s00 = fmaf(WAC, ec0*ec0, Ts00);
        float Ts01 = fmaf(Od00, Q0, xi0*et0);
        Ts01 = fmaf(xi1, et1, Ts01); Ts01 = fmaf(Od01, Q1, Ts01);
        Ts01 = fmaf(ec0, et23, Ts01);
        float s01 = fmaf(WCC, ec0*ec1, Ts01);
        float Ts11 = fmaf(Q0,Q0, et0*et0);
        Ts11 = fmaf(et1,et1,Ts11); Ts11 = fmaf(Q1,Q1,Ts11);
        Ts11 = fmaf(et2,et2,Ts11); Ts11 = fmaf(Q2,Q2,Ts11);
        Ts11 = fmaf(et3,et3,Ts11); Ts11 = fmaf(Q3,Q3,Ts11);
        float s11 = fmaf(WCC, ec1*ec1, Ts11);

        // pz' = CUT*P_zy
        float pz00 = fmaf(D01, Od01, D00*Od00);
        float pz01 = fmaf(D01, Q1, D00*Q0);
        float Tp10 = fmaf(D10, Od00, eps_a*xi0);
        Tp10 = fmaf(eps_c, xi1, Tp10); Tp10 = fmaf(D11, Od01, Tp10);
        float pz10 = fmaf(-WA, q*ec0, Tp10);
        float et123 = et1 + et23;
        float Tp11 = fmaf(D10, Q0, eps_a*et0);
        Tp11 = fmaf(eps_c, et123, Tp11);
        Tp11 = fmaf(D11, Q1, Tp11);
        Tp11 = fmaf(D12, Q2, Tp11);
        Tp11 = fmaf(D13, Q3, Tp11);
        float pz11 = fmaf(-WC0, q*ec1, Tp11);
        float pz20 = fmaf(g21, Od01, g20*Od00);
        float pz30 = fmaf(g31, Od01, g30*Od00);
        float pz21 = fmaf(g21, Q1, g20*Q0); pz21 = fmaf(g22, Q2, pz21);
        float pz31 = fmaf(g31, Q1, g30*Q0); pz31 = fmaf(g32, Q2, pz31);
        pz31 = fmaf(g33, Q3, pz31);

        // K = pz' * (S')^-1 (true gain; CUT cancels)
        float sg00 = s00 + RSG, sg11 = s11 + RSG;
        float det  = fmaf(sg00, sg11, -(s01*s01));
        float idet = frcp(det);
        float i00 = sg11*idet, i01 = -(s01*idet), i11 = sg00*idet;
        float K00 = fmaf(pz01,i01, pz00*i00), K01 = fmaf(pz01,i11, pz00*i01);
        float K10 = fmaf(pz11,i01, pz10*i00), K11 = fmaf(pz11,i11, pz10*i01);
        float K20 = fmaf(pz21,i01, pz20*i00), K21 = fmaf(pz21,i11, pz20*i01);
        float K30 = fmaf(pz31,i01, pz30*i00), K31 = fmaf(pz31,i11, pz30*i01);

        float nu0 = yv0 - yp0, nu1 = yv1 - yp1;
        z0v = fmaf(K00,nu0, fmaf(K01,nu1, X00));
        z1v = fmaf(K10,nu0, fmaf(K11,nu1, zp1));
        z2v = fmaf(K20,nu0, fmaf(K21,nu1, z2v));
        z3v = fmaf(K30,nu0, fmaf(K31,nu1, z3v));

        // Pc_post = B' - K*pz'^T
        P00 = fmaf(-K00,pz00, fmaf(-K01,pz01, B00p));
        P01 = fmaf(-K00,pz10, fmaf(-K01,pz11, B01p));
        P02 = fmaf(-K00,pz20, fmaf(-K01,pz21, B02p));
        P03 = fmaf(-K00,pz30, fmaf(-K01,pz31, B03p));
        P11 = fmaf(-K10,pz10, fmaf(-K11,pz11, B11p));
        P12 = fmaf(-K10,pz20, fmaf(-K11,pz21, B12p));
        P13 = fmaf(-K10,pz30, fmaf(-K11,pz31, B13p));
        P22 = fmaf(-K20,pz20, fmaf(-K21,pz21, B22p));
        P23 = fmaf(-K20,pz30, fmaf(-K21,pz31, B23p));
        P33 = fmaf(-K30,pz30, fmaf(-K31,pz31, B33p));
    }

    __device__ __forceinline__ void store(int t){
        *reinterpret_cast<float4*>(ob + 4*t) = make_float4(z0v,z1v,z2v,z3v);
    }
};

// R7 lesson: __launch_bounds__ 2nd arg (min waves/EU) DEFAULTS to 1 — (64,1)
// was a no-op. The allocator's occupancy heuristic kept a ~48-VGPR budget and
// spilled filter B to scratch (WRITE_SIZE 70->174 MB). Fix: pin waves/EU to
// exactly 1 via amdgpu_waves_per_eu(1,1) -> occupancy can't exceed 1 wave/SIMD
// (physically true anyway: 128 waves on 1024 SIMDs), so the full 512-VGPR file
// is usable and spilling is pointless.
__global__
__attribute__((amdgpu_flat_work_group_size(64, 64)))
__attribute__((amdgpu_waves_per_eu(1, 1)))
void ukf_kernel(const float* __restrict__ yg, const float* __restrict__ ug,
                const float* __restrict__ z0g, const float* __restrict__ P0g,
                float* __restrict__ outg)
{
    const int tid = blockIdx.x*64 + threadIdx.x;

    UKF A, B;
    A.load(yg,ug,z0g,P0g,outg, tid);
    B.load(yg,ug,z0g,P0g,outg, tid + BB/2);

    float2 ayc = *reinterpret_cast<const float2*>(A.yb);
    float2 byc = *reinterpret_cast<const float2*>(B.yb);
    A.ynext = *reinterpret_cast<const float2*>(A.yb + 2);
    B.ynext = *reinterpret_cast<const float2*>(B.yb + 2);
    A.unext = A.ub[0];
    B.unext = B.ub[0];

    // ---- t = 0 (no dynamics) ----
    A.chol();               B.chol();
    A.predict0();           B.predict0();
    A.update(ayc.x, ayc.y); B.update(byc.x, byc.y);
    A.store(0);             B.store(0);

    // ---- main loop t = 1..255, two independent filters interleaved ----
    #pragma unroll 1
    for (int t = 1; t < TT; ++t) {
        float ay0=A.ynext.x, ay1=A.ynext.y, au=A.unext;
        float by0=B.ynext.x, by1=B.ynext.y, bu=B.unext;
        int tn = (t+1 < TT) ? (t+1) : (TT-1);
        A.ynext = *reinterpret_cast<const float2*>(A.yb + 2*tn);
        B.ynext = *reinterpret_cast<const float2*>(B.yb + 2*tn);
        A.unext = A.ub[t];
        B.unext = B.ub[t];

        A.chol();            B.chol();
        A.predict(au);       B.predict(bu);
        A.update(ay0, ay1);  B.update(by0, by1);
        A.store(t);          B.store(t);
    }
}

extern "C" void kernel_launch(void* const* d_in, const int* in_sizes, int n_in,
                              void* d_out, int out_size, void* d_ws, size_t ws_size,
                              hipStream_t stream) {
    const float* y  = (const float*)d_in[0];   // (B,T,NY)
    const float* u  = (const float*)d_in[1];   // (B,T)
    const float* z0 = (const float*)d_in[2];   // (B,N)
    const float* P0 = (const float*)d_in[3];   // (B,N,N)
    float* out = (float*)d_out;                // (B,T,N)

    ukf_kernel<<<dim3((BB/2)/64), dim3(64), 0, stream>>>(y, u, z0, P0, out);
}